// Round 1
// baseline (6287.169 us; speedup 1.0000x reference)
//
#include <hip/hip_runtime.h>
#include <math.h>

#define NT 4096
#define DM 1152
#define NH 16
#define DH 72
#define KRET 1638
#define NPR (NT - KRET)
#define SCALE 0.11785113019775793f

// ---------------- GEMM: C[M,Nn] = A[M,K] @ B[K,Nn] (+bias) -----------------
__global__ __launch_bounds__(256) void gemm64(
    const float* __restrict__ A, const float* __restrict__ B,
    float* __restrict__ C, const float* __restrict__ bias,
    int M, int Nn, int K)
{
    __shared__ float As[16][65];
    __shared__ float Bs[16][64];
    const int tid = threadIdx.x;
    const int tcol = tid & 15, trow = tid >> 4;
    const int aBase = blockIdx.y * 64;
    const int bBase = blockIdx.x * 64;
    float acc[4][4] = {};
    for (int k0 = 0; k0 < K; k0 += 16) {
#pragma unroll
        for (int l = 0; l < 4; ++l) {
            int idx = tid + l * 256;
            int m = idx >> 4, kk = idx & 15;
            As[kk][m] = A[(size_t)(aBase + m) * K + k0 + kk];
        }
#pragma unroll
        for (int l = 0; l < 4; ++l) {
            int idx = tid + l * 256;
            int kk = idx >> 6, n = idx & 63;
            Bs[kk][n] = B[(size_t)(k0 + kk) * Nn + bBase + n];
        }
        __syncthreads();
#pragma unroll
        for (int kk = 0; kk < 16; ++kk) {
            float ra[4], rb[4];
#pragma unroll
            for (int i = 0; i < 4; ++i) ra[i] = As[kk][trow * 4 + i];
#pragma unroll
            for (int j = 0; j < 4; ++j) rb[j] = Bs[kk][tcol * 4 + j];
#pragma unroll
            for (int i = 0; i < 4; ++i)
#pragma unroll
                for (int j = 0; j < 4; ++j)
                    acc[i][j] += ra[i] * rb[j];
        }
        __syncthreads();
    }
#pragma unroll
    for (int i = 0; i < 4; ++i) {
        int row = aBase + trow * 4 + i;
#pragma unroll
        for (int j = 0; j < 4; ++j) {
            int col = bBase + tcol * 4 + j;
            float vv = acc[i][j];
            if (bias) vv += bias[col];
            C[(size_t)row * Nn + col] = vv;
        }
    }
}

// ---------------- S = scale * q_h k_h^T  (64x64 tiles, K = 72) --------------
__global__ __launch_bounds__(256) void qk_head(
    const float* __restrict__ q, const float* __restrict__ k,
    float* __restrict__ S, int head)
{
    __shared__ float qs[64][DH + 1];
    __shared__ float ks[64][DH + 1];
    const int tid = threadIdx.x;
    const int i0 = blockIdx.y * 64, j0 = blockIdx.x * 64;
    const int hb = head * DH;
    for (int idx = tid; idx < 64 * DH; idx += 256) {
        int r = idx / DH, d = idx - r * DH;
        qs[r][d] = q[(size_t)(i0 + r) * DM + hb + d];
        ks[r][d] = k[(size_t)(j0 + r) * DM + hb + d];
    }
    __syncthreads();
    const int tcol = tid & 15, trow = tid >> 4;
    float acc[4][4] = {};
#pragma unroll 4
    for (int d = 0; d < DH; ++d) {
        float ra[4], rb[4];
#pragma unroll
        for (int i = 0; i < 4; ++i) ra[i] = qs[trow * 4 + i][d];
#pragma unroll
        for (int j = 0; j < 4; ++j) rb[j] = ks[tcol * 4 + j][d];
#pragma unroll
        for (int i = 0; i < 4; ++i)
#pragma unroll
            for (int j = 0; j < 4; ++j)
                acc[i][j] += ra[i] * rb[j];
    }
#pragma unroll
    for (int i = 0; i < 4; ++i)
#pragma unroll
        for (int j = 0; j < 4; ++j)
            S[(size_t)(i0 + trow * 4 + i) * NT + j0 + tcol * 4 + j] = acc[i][j] * SCALE;
}

// ------- row softmax in LDS; writes P back to S and attn += P/16 ------------
__global__ __launch_bounds__(256) void softmax_acc(
    float* __restrict__ S, float* __restrict__ attn)
{
    __shared__ float row[NT];
    __shared__ float red[8];
    const int tid = threadIdx.x;
    float* srow = S + (size_t)blockIdx.x * NT;
    float m = -INFINITY;
    for (int j = tid; j < NT; j += 256) { float vv = srow[j]; row[j] = vv; m = fmaxf(m, vv); }
#pragma unroll
    for (int o = 32; o; o >>= 1) m = fmaxf(m, __shfl_xor(m, o));
    if ((tid & 63) == 0) red[tid >> 6] = m;
    __syncthreads();
    m = fmaxf(fmaxf(red[0], red[1]), fmaxf(red[2], red[3]));
    float s = 0.f;
    for (int j = tid; j < NT; j += 256) { float e = expf(row[j] - m); row[j] = e; s += e; }
#pragma unroll
    for (int o = 32; o; o >>= 1) s += __shfl_xor(s, o);
    if ((tid & 63) == 0) red[4 + (tid >> 6)] = s;
    __syncthreads();
    s = (red[4] + red[5]) + (red[6] + red[7]);
    float* arow = attn + (size_t)blockIdx.x * NT;
    for (int j = tid; j < NT; j += 256) {
        float p = row[j] / s;
        srow[j] = p;
        arow[j] += p * 0.0625f;
    }
}

// ---------------- O_h = P @ v_h  (16 rows/block, 4 rows/thread) -------------
__global__ __launch_bounds__(288) void pv_head(
    const float* __restrict__ S, const float* __restrict__ v,
    float* __restrict__ o, int head)
{
    __shared__ float vt[64][DH];
    __shared__ float pt[16][64];
    const int tid = threadIdx.x;
    const int d = tid % DH;
    const int rg = (tid / DH) * 4;
    const int row0 = blockIdx.x * 16;
    const int hb = head * DH;
    float acc[4] = {0.f, 0.f, 0.f, 0.f};
    for (int c = 0; c < NT; c += 64) {
        for (int idx = tid; idx < 64 * DH; idx += 288) {
            int jj = idx / DH, dd = idx - jj * DH;
            vt[jj][dd] = v[(size_t)(c + jj) * DM + hb + dd];
        }
        for (int idx = tid; idx < 16 * 64; idx += 288) {
            pt[idx >> 6][idx & 63] = S[(size_t)(row0 + (idx >> 6)) * NT + c + (idx & 63)];
        }
        __syncthreads();
#pragma unroll 8
        for (int jj = 0; jj < 64; ++jj) {
            float vv = vt[jj][d];
#pragma unroll
            for (int rr = 0; rr < 4; ++rr)
                acc[rr] += pt[rg + rr][jj] * vv;
        }
        __syncthreads();
    }
#pragma unroll
    for (int rr = 0; rr < 4; ++rr)
        o[(size_t)(row0 + rg + rr) * DM + hb + d] = acc[rr];
}

// ---------------- pagerank power iteration ---------------------------------
__global__ __launch_bounds__(256) void init_dist(float* __restrict__ d)
{
    int t = blockIdx.x * 256 + threadIdx.x;
    if (t < NT) d[t] = 1.0f / NT;
}

__global__ __launch_bounds__(256) void power_a(
    const float* __restrict__ attn, const float* __restrict__ din,
    float* __restrict__ part)
{
    int j = blockIdx.x * 256 + threadIdx.x;
    int i0 = blockIdx.y * 128;
    float acc = 0.f;
    for (int i = i0; i < i0 + 128; ++i)
        acc += din[i] * attn[(size_t)i * NT + j];
    part[(size_t)blockIdx.y * NT + j] = acc;
}

__global__ __launch_bounds__(256) void power_b(
    const float* __restrict__ part, float* __restrict__ dout)
{
    int j = blockIdx.x * 256 + threadIdx.x;
    float acc = 0.f;
    for (int ib = 0; ib < 32; ++ib) acc += part[(size_t)ib * NT + j];
    dout[j] = acc;
}

// ---------------- top-k via rank counting (jax tie rule) --------------------
__global__ __launch_bounds__(256) void rank_kernel(
    const float* __restrict__ imp, int* __restrict__ rank, int* __restrict__ prank)
{
    __shared__ float si[NT];
    for (int t = threadIdx.x; t < NT; t += 256) si[t] = imp[t];
    __syncthreads();
    int i = blockIdx.x * 256 + threadIdx.x;
    float mv = si[i];
    int r = 0, rp = 0;
    for (int j = 0; j < NT; ++j) {
        float vj = si[j];
        int tie_low = (vj == mv) && (j < i);
        r  += (vj > mv) || tie_low;
        rp += (vj < mv) || tie_low;
    }
    rank[i] = r;
    prank[i] = rp;
}

__global__ __launch_bounds__(256) void scatter_topk(
    const int* __restrict__ rank, const int* __restrict__ prank,
    float* __restrict__ out_imps, float* __restrict__ out_prune,
    int* __restrict__ imp_rows, int* __restrict__ prune_cols)
{
    __shared__ unsigned char fr[NT];
    __shared__ unsigned char fp[NT];
    for (int t = threadIdx.x; t < NT; t += 256) {
        fr[t] = rank[t] < KRET;
        fp[t] = prank[t] < NPR;
    }
    __syncthreads();
    int i = blockIdx.x * 256 + threadIdx.x;
    int cr = 0, cp = 0;
    for (int j = 0; j < i; ++j) { cr += fr[j]; cp += fp[j]; }
    if (fr[i]) { out_imps[cr] = (float)i; imp_rows[cr] = i; }
    if (fp[i]) { out_prune[cp] = (float)i; prune_cols[cp] = i; }
}

// --------- per-column argmax over retained rows (first-occurrence) ----------
__global__ __launch_bounds__(256) void argmax_cols(
    const float* __restrict__ attn, const int* __restrict__ imp_rows,
    int* __restrict__ maxind)
{
    __shared__ int rows[KRET];
    for (int t = threadIdx.x; t < KRET; t += 256) rows[t] = imp_rows[t];
    __syncthreads();
    int j = blockIdx.x * 256 + threadIdx.x;
    float best = -INFINITY;
    int bi = 0;
    for (int r = 0; r < KRET; ++r) {
        float val = attn[(size_t)rows[r] * NT + j];
        if (val > best) { best = val; bi = r; }
    }
    maxind[j] = bi;
}

__global__ __launch_bounds__(256) void finalize(
    const float* __restrict__ dist, const int* __restrict__ prune_cols,
    const int* __restrict__ maxind, float* __restrict__ out_imp,
    float* __restrict__ out_simi)
{
    int t = blockIdx.x * 256 + threadIdx.x;
    if (t < NT) out_imp[t] = dist[t];
    if (t < NPR) out_simi[t] = (float)maxind[prune_cols[t]];
}

extern "C" void kernel_launch(void* const* d_in, const int* in_sizes, int n_in,
                              void* d_out, int out_size, void* d_ws, size_t ws_size,
                              hipStream_t stream)
{
    const float* x  = (const float*)d_in[0];
    const float* Wq = (const float*)d_in[1];
    const float* Wk = (const float*)d_in[2];
    const float* Wv = (const float*)d_in[3];
    const float* Wo = (const float*)d_in[4];
    const float* bo = (const float*)d_in[5];
    float* out = (float*)d_out;

    // workspace layout (floats); total ~211 MB
    float* ws = (float*)d_ws;
    size_t off = 0;
    float* q    = ws + off; off += (size_t)NT * DM;
    float* kbuf = ws + off; off += (size_t)NT * DM;
    float* vbuf = ws + off; off += (size_t)NT * DM;
    float* otmp = ws + off; off += (size_t)NT * DM;
    float* attn = ws + off; off += (size_t)NT * NT;
    float* S    = ws + off; off += (size_t)NT * NT;
    float* dist0 = ws + off; off += NT;
    float* dist1 = ws + off; off += NT;
    float* partial = ws + off; off += 32 * NT;
    int* rank      = (int*)(ws + off); off += NT;
    int* prank     = (int*)(ws + off); off += NT;
    int* imp_rows  = (int*)(ws + off); off += 2048;
    int* prune_cols= (int*)(ws + off); off += 2560;
    int* maxind    = (int*)(ws + off); off += NT;

    // output layout (floats, concatenated in reference return order)
    float* out_out   = out;
    float* out_imp   = out + (size_t)NT * DM;
    float* out_imps  = out_imp + NT;
    float* out_prune = out_imps + KRET;
    float* out_simi  = out_prune + NPR;

    dim3 g1(DM / 64, NT / 64);
    gemm64<<<g1, 256, 0, stream>>>(x, Wq, q,    nullptr, NT, DM, DM);
    gemm64<<<g1, 256, 0, stream>>>(x, Wk, kbuf, nullptr, NT, DM, DM);
    gemm64<<<g1, 256, 0, stream>>>(x, Wv, vbuf, nullptr, NT, DM, DM);

    hipMemsetAsync(attn, 0, (size_t)NT * NT * sizeof(float), stream);

    dim3 g2(NT / 64, NT / 64);
    for (int h = 0; h < NH; ++h) {
        qk_head<<<g2, 256, 0, stream>>>(q, kbuf, S, h);
        softmax_acc<<<NT, 256, 0, stream>>>(S, attn);
        pv_head<<<NT / 16, 288, 0, stream>>>(S, vbuf, otmp, h);
    }

    gemm64<<<g1, 256, 0, stream>>>(otmp, Wo, out_out, bo, NT, DM, DM);

    init_dist<<<16, 256, 0, stream>>>(dist0);
    float* da = dist0;
    float* db = dist1;
    for (int it = 0; it < 5; ++it) {
        power_a<<<dim3(16, 32), 256, 0, stream>>>(attn, da, partial);
        power_b<<<16, 256, 0, stream>>>(partial, db);
        float* t = da; da = db; db = t;
    }

    rank_kernel<<<16, 256, 0, stream>>>(da, rank, prank);
    scatter_topk<<<16, 256, 0, stream>>>(rank, prank, out_imps, out_prune,
                                         imp_rows, prune_cols);
    argmax_cols<<<16, 256, 0, stream>>>(attn, imp_rows, maxind);
    finalize<<<16, 256, 0, stream>>>(da, prune_cols, maxind, out_imp, out_simi);
}

// Round 2
// 2872.128 us; speedup vs baseline: 2.1890x; 2.1890x over previous
//
#include <hip/hip_runtime.h>
#include <math.h>

#define NT 4096
#define DM 1152
#define NH 16
#define DH 72
#define KRET 1638
#define NPR (NT - KRET)
#define KS 8
#define SCALE 0.11785113019775793f

typedef __attribute__((ext_vector_type(8))) short bf16x8;
typedef __attribute__((ext_vector_type(4))) float f32x4;
typedef unsigned short ushort_t;

__device__ inline ushort_t f2b(float f) {
    union { float f; unsigned int u; } v; v.f = f;
    unsigned int u = v.u;
    return (ushort_t)((u + 0x7FFFu + ((u >> 16) & 1u)) >> 16);
}

// ---------------- fp32 GEMM (Q,K projections — ranking-critical) ------------
__global__ __launch_bounds__(256) void gemm64(
    const float* __restrict__ A, const float* __restrict__ B,
    float* __restrict__ C, const float* __restrict__ bias,
    int M, int Nn, int K)
{
    __shared__ float As[16][65];
    __shared__ float Bs[16][64];
    const int tid = threadIdx.x;
    const int tcol = tid & 15, trow = tid >> 4;
    const int aBase = blockIdx.y * 64;
    const int bBase = blockIdx.x * 64;
    float acc[4][4] = {};
    for (int k0 = 0; k0 < K; k0 += 16) {
#pragma unroll
        for (int l = 0; l < 4; ++l) {
            int idx = tid + l * 256;
            int m = idx >> 4, kk = idx & 15;
            As[kk][m] = A[(size_t)(aBase + m) * K + k0 + kk];
        }
#pragma unroll
        for (int l = 0; l < 4; ++l) {
            int idx = tid + l * 256;
            int kk = idx >> 6, n = idx & 63;
            Bs[kk][n] = B[(size_t)(k0 + kk) * Nn + bBase + n];
        }
        __syncthreads();
#pragma unroll
        for (int kk = 0; kk < 16; ++kk) {
            float ra[4], rb[4];
#pragma unroll
            for (int i = 0; i < 4; ++i) ra[i] = As[kk][trow * 4 + i];
#pragma unroll
            for (int j = 0; j < 4; ++j) rb[j] = Bs[kk][tcol * 4 + j];
#pragma unroll
            for (int i = 0; i < 4; ++i)
#pragma unroll
                for (int j = 0; j < 4; ++j)
                    acc[i][j] += ra[i] * rb[j];
        }
        __syncthreads();
    }
#pragma unroll
    for (int i = 0; i < 4; ++i) {
        int row = aBase + trow * 4 + i;
#pragma unroll
        for (int j = 0; j < 4; ++j) {
            int col = bBase + tcol * 4 + j;
            float vv = acc[i][j];
            if (bias) vv += bias[col];
            C[(size_t)row * Nn + col] = vv;
        }
    }
}

// ---------------- helpers: convert / transpose ------------------------------
__global__ __launch_bounds__(256) void convertX(
    const float* __restrict__ in, ushort_t* __restrict__ out, int nElem)
{
    int i = blockIdx.x * 256 + threadIdx.x;
    int stride = gridDim.x * 256;
    for (; i < nElem; i += stride) out[i] = f2b(in[i]);
}

__global__ __launch_bounds__(256) void transposeW(
    const float* __restrict__ W, ushort_t* __restrict__ WT, int n)
{
    __shared__ ushort_t t[32][33];
    int bx = blockIdx.x * 32, by = blockIdx.y * 32;
    int tx = threadIdx.x & 31, ty = threadIdx.x >> 5;
    for (int i = ty; i < 32; i += 8)
        t[i][tx] = f2b(W[(size_t)(by + i) * n + bx + tx]);
    __syncthreads();
    for (int i = ty; i < 32; i += 8)
        WT[(size_t)(bx + i) * n + by + tx] = t[tx][i];
}

__global__ __launch_bounds__(256) void transposeB16(
    const ushort_t* __restrict__ in, ushort_t* __restrict__ out,
    int rows, int cols)
{
    __shared__ ushort_t t[32][33];
    int bx = blockIdx.x * 32, by = blockIdx.y * 32;
    int tx = threadIdx.x & 31, ty = threadIdx.x >> 5;
    for (int i = ty; i < 32; i += 8)
        t[i][tx] = in[(size_t)(by + i) * cols + bx + tx];
    __syncthreads();
    for (int i = ty; i < 32; i += 8)
        out[(size_t)(bx + i) * rows + by + tx] = t[tx][i];
}

// ---------------- bf16 MFMA GEMM: C = A[MxK] @ BT[NxK]^T (+bias) ------------
__global__ __launch_bounds__(256) void gemm_mfma(
    const ushort_t* __restrict__ A, const ushort_t* __restrict__ BT,
    const float* __restrict__ bias, void* __restrict__ C, int cbf16,
    int M, int Nn, int K)
{
    const int tid = threadIdx.x;
    const int wave = tid >> 6, lane = tid & 63;
    const int r = lane & 15, g = lane >> 4;
    const int row0 = blockIdx.y * 64 + wave * 16;
    const int col0 = blockIdx.x * 64;
    const ushort_t* arow = A + (size_t)(row0 + r) * K;
    f32x4 acc[4] = {};
    for (int k0 = 0; k0 < K; k0 += 32) {
        bf16x8 a = *(const bf16x8*)(arow + k0 + g * 8);
#pragma unroll
        for (int t = 0; t < 4; ++t) {
            bf16x8 b = *(const bf16x8*)(BT + (size_t)(col0 + t * 16 + r) * K + k0 + g * 8);
            acc[t] = __builtin_amdgcn_mfma_f32_16x16x32_bf16(a, b, acc[t], 0, 0, 0);
        }
    }
#pragma unroll
    for (int t = 0; t < 4; ++t) {
        int col = col0 + t * 16 + r;
        float bv = bias ? bias[col] : 0.f;
#pragma unroll
        for (int j = 0; j < 4; ++j) {
            int row = row0 + g * 4 + j;
            float vv = acc[t][j] + bv;
            if (cbf16) ((ushort_t*)C)[(size_t)row * Nn + col] = f2b(vv);
            else       ((float*)C)[(size_t)row * Nn + col] = vv;
        }
    }
}

// ---------------- S = scale * q_h k_h^T  (fp32, ranking-critical) -----------
__global__ __launch_bounds__(256) void qk_head(
    const float* __restrict__ q, const float* __restrict__ k,
    float* __restrict__ S, int head)
{
    __shared__ float qs[64][DH + 1];
    __shared__ float ks[64][DH + 1];
    const int tid = threadIdx.x;
    const int i0 = blockIdx.y * 64, j0 = blockIdx.x * 64;
    const int hb = head * DH;
    for (int idx = tid; idx < 64 * DH; idx += 256) {
        int r = idx / DH, d = idx - r * DH;
        qs[r][d] = q[(size_t)(i0 + r) * DM + hb + d];
        ks[r][d] = k[(size_t)(j0 + r) * DM + hb + d];
    }
    __syncthreads();
    const int tcol = tid & 15, trow = tid >> 4;
    float acc[4][4] = {};
#pragma unroll 4
    for (int d = 0; d < DH; ++d) {
        float ra[4], rb[4];
#pragma unroll
        for (int i = 0; i < 4; ++i) ra[i] = qs[trow * 4 + i][d];
#pragma unroll
        for (int j = 0; j < 4; ++j) rb[j] = ks[tcol * 4 + j][d];
#pragma unroll
        for (int i = 0; i < 4; ++i)
#pragma unroll
            for (int j = 0; j < 4; ++j)
                acc[i][j] += ra[i] * rb[j];
    }
#pragma unroll
    for (int i = 0; i < 4; ++i)
#pragma unroll
        for (int j = 0; j < 4; ++j)
            S[(size_t)(i0 + trow * 4 + i) * NT + j0 + tcol * 4 + j] = acc[i][j] * SCALE;
}

// --- row softmax: attn += P/16 (fp32 exact), P written bf16 in-place in S ---
__global__ __launch_bounds__(256) void softmax_acc(
    float* __restrict__ S, float* __restrict__ attn)
{
    __shared__ float row[NT];
    __shared__ float red[8];
    const int tid = threadIdx.x;
    float* srow = S + (size_t)blockIdx.x * NT;
    float m = -INFINITY;
    for (int j = tid; j < NT; j += 256) { float vv = srow[j]; row[j] = vv; m = fmaxf(m, vv); }
#pragma unroll
    for (int o = 32; o; o >>= 1) m = fmaxf(m, __shfl_xor(m, o));
    if ((tid & 63) == 0) red[tid >> 6] = m;
    __syncthreads();
    m = fmaxf(fmaxf(red[0], red[1]), fmaxf(red[2], red[3]));
    float s = 0.f;
    for (int j = tid; j < NT; j += 256) { float e = expf(row[j] - m); row[j] = e; s += e; }
#pragma unroll
    for (int o = 32; o; o >>= 1) s += __shfl_xor(s, o);
    if ((tid & 63) == 0) red[4 + (tid >> 6)] = s;
    __syncthreads();
    s = (red[4] + red[5]) + (red[6] + red[7]);
    float* arow = attn + (size_t)blockIdx.x * NT;
    ushort_t* pb = (ushort_t*)srow;   // bf16 P packed into first half of the row
    for (int j = tid; j < NT; j += 256) {
        float p = row[j] / s;
        pb[j] = f2b(p);
        arow[j] += p * 0.0625f;
    }
}

// ---------------- O_h = P @ v_h via MFMA (k-split partials) -----------------
__global__ __launch_bounds__(256) void pv_mfma(
    const float* __restrict__ Sbuf, const ushort_t* __restrict__ vtb,
    float* __restrict__ part, int head)
{
    const int tid = threadIdx.x;
    const int wave = tid >> 6, lane = tid & 63;
    const int r = lane & 15, g = lane >> 4;
    const int row0 = blockIdx.x * 64 + wave * 16;
    const int k0base = blockIdx.y * (NT / KS);
    const int hb = head * DH;
    const ushort_t* arow = (const ushort_t*)(Sbuf + (size_t)(row0 + r) * NT);
    f32x4 acc[5] = {};
    for (int kk = 0; kk < NT / KS; kk += 32) {
        int k0 = k0base + kk;
        bf16x8 a = *(const bf16x8*)(arow + k0 + g * 8);
#pragma unroll
        for (int t = 0; t < 5; ++t) {
            int col = t * 16 + r;
            bf16x8 b = {};
            if (col < DH)
                b = *(const bf16x8*)(vtb + (size_t)(hb + col) * NT + k0 + g * 8);
            acc[t] = __builtin_amdgcn_mfma_f32_16x16x32_bf16(a, b, acc[t], 0, 0, 0);
        }
    }
    float* pp = part + (size_t)blockIdx.y * (NT * DH);
#pragma unroll
    for (int t = 0; t < 5; ++t) {
        int col = t * 16 + r;
        if (col < DH) {
#pragma unroll
            for (int j = 0; j < 4; ++j) {
                int row = row0 + g * 4 + j;
                pp[(size_t)row * DH + col] = acc[t][j];
            }
        }
    }
}

__global__ __launch_bounds__(256) void pv_reduce(
    const float* __restrict__ part, ushort_t* __restrict__ otmpb, int head)
{
    int idx = blockIdx.x * 256 + threadIdx.x;
    if (idx >= NT * DH) return;
    int row = idx / DH, col = idx - row * DH;
    float s = 0.f;
#pragma unroll
    for (int ks = 0; ks < KS; ++ks) s += part[(size_t)ks * (NT * DH) + idx];
    otmpb[(size_t)row * DM + head * DH + col] = f2b(s);
}

// ---------------- pagerank power iteration (fp32, unchanged) ----------------
__global__ __launch_bounds__(256) void init_dist(float* __restrict__ d)
{
    int t = blockIdx.x * 256 + threadIdx.x;
    if (t < NT) d[t] = 1.0f / NT;
}

__global__ __launch_bounds__(256) void power_a(
    const float* __restrict__ attn, const float* __restrict__ din,
    float* __restrict__ part)
{
    int j = blockIdx.x * 256 + threadIdx.x;
    int i0 = blockIdx.y * 128;
    float acc = 0.f;
    for (int i = i0; i < i0 + 128; ++i)
        acc += din[i] * attn[(size_t)i * NT + j];
    part[(size_t)blockIdx.y * NT + j] = acc;
}

__global__ __launch_bounds__(256) void power_b(
    const float* __restrict__ part, float* __restrict__ dout)
{
    int j = blockIdx.x * 256 + threadIdx.x;
    float acc = 0.f;
    for (int ib = 0; ib < 32; ++ib) acc += part[(size_t)ib * NT + j];
    dout[j] = acc;
}

// ---------------- top-k via rank counting (jax tie rule) --------------------
__global__ __launch_bounds__(256) void rank_kernel(
    const float* __restrict__ imp, int* __restrict__ rank, int* __restrict__ prank)
{
    __shared__ float si[NT];
    for (int t = threadIdx.x; t < NT; t += 256) si[t] = imp[t];
    __syncthreads();
    int i = blockIdx.x * 256 + threadIdx.x;
    float mv = si[i];
    int r = 0, rp = 0;
    for (int j = 0; j < NT; ++j) {
        float vj = si[j];
        int tie_low = (vj == mv) && (j < i);
        r  += (vj > mv) || tie_low;
        rp += (vj < mv) || tie_low;
    }
    rank[i] = r;
    prank[i] = rp;
}

__global__ __launch_bounds__(256) void scatter_topk(
    const int* __restrict__ rank, const int* __restrict__ prank,
    float* __restrict__ out_imps, float* __restrict__ out_prune,
    int* __restrict__ imp_rows, int* __restrict__ prune_cols)
{
    __shared__ unsigned char fr[NT];
    __shared__ unsigned char fp[NT];
    for (int t = threadIdx.x; t < NT; t += 256) {
        fr[t] = rank[t] < KRET;
        fp[t] = prank[t] < NPR;
    }
    __syncthreads();
    int i = blockIdx.x * 256 + threadIdx.x;
    int cr = 0, cp = 0;
    for (int j = 0; j < i; ++j) { cr += fr[j]; cp += fp[j]; }
    if (fr[i]) { out_imps[cr] = (float)i; imp_rows[cr] = i; }
    if (fp[i]) { out_prune[cp] = (float)i; prune_cols[cp] = i; }
}

__global__ __launch_bounds__(256) void argmax_cols(
    const float* __restrict__ attn, const int* __restrict__ imp_rows,
    int* __restrict__ maxind)
{
    __shared__ int rows[KRET];
    for (int t = threadIdx.x; t < KRET; t += 256) rows[t] = imp_rows[t];
    __syncthreads();
    int j = blockIdx.x * 256 + threadIdx.x;
    float best = -INFINITY;
    int bi = 0;
    for (int r = 0; r < KRET; ++r) {
        float val = attn[(size_t)rows[r] * NT + j];
        if (val > best) { best = val; bi = r; }
    }
    maxind[j] = bi;
}

__global__ __launch_bounds__(256) void finalize(
    const float* __restrict__ dist, const int* __restrict__ prune_cols,
    const int* __restrict__ maxind, float* __restrict__ out_imp,
    float* __restrict__ out_simi)
{
    int t = blockIdx.x * 256 + threadIdx.x;
    if (t < NT) out_imp[t] = dist[t];
    if (t < NPR) out_simi[t] = (float)maxind[prune_cols[t]];
}

extern "C" void kernel_launch(void* const* d_in, const int* in_sizes, int n_in,
                              void* d_out, int out_size, void* d_ws, size_t ws_size,
                              hipStream_t stream)
{
    const float* x  = (const float*)d_in[0];
    const float* Wq = (const float*)d_in[1];
    const float* Wk = (const float*)d_in[2];
    const float* Wv = (const float*)d_in[3];
    const float* Wo = (const float*)d_in[4];
    const float* bo = (const float*)d_in[5];
    float* out = (float*)d_out;

    // workspace layout (float units) — ~206 MB total, with aliasing
    float* ws = (float*)d_ws;
    size_t off = 0;
    float* q    = ws + off; off += (size_t)NT * DM;                 // fp32
    float* kbuf = ws + off; off += (size_t)NT * DM;                 // fp32
    float* S    = ws + off; off += (size_t)NT * NT;                 // fp32 (Pb bf16 aliased in)
    float* attn = ws + off; off += (size_t)NT * NT;                 // fp32
    ushort_t* xb  = (ushort_t*)(ws + off); off += ((size_t)NT * DM) / 2;   // bf16; later otmpb
    ushort_t* WvT = (ushort_t*)(ws + off); off += ((size_t)DM * DM) / 2;   // bf16
    ushort_t* WoT = (ushort_t*)(ws + off); off += ((size_t)DM * DM) / 2;   // bf16
    float* vb_part = ws + off; off += (size_t)NT * DM / 2;          // vb bf16, later part fp32 [KS][NT][DH]
    ushort_t* vtb = (ushort_t*)(ws + off); off += ((size_t)NT * DM) / 2;   // bf16 v^T [DM][NT]
    float* dist0 = ws + off; off += NT;
    float* dist1 = ws + off; off += NT;
    float* partial = ws + off; off += 32 * NT;
    int* rank      = (int*)(ws + off); off += NT;
    int* prank     = (int*)(ws + off); off += NT;
    int* imp_rows  = (int*)(ws + off); off += 2048;
    int* prune_cols= (int*)(ws + off); off += 2560;
    int* maxind    = (int*)(ws + off); off += NT;

    ushort_t* vb = (ushort_t*)vb_part;
    float* part = vb_part;
    ushort_t* otmpb = xb;

    // output layout
    float* out_out   = out;
    float* out_imp   = out + (size_t)NT * DM;
    float* out_imps  = out_imp + NT;
    float* out_prune = out_imps + KRET;
    float* out_simi  = out_prune + NPR;

    // --- projections ---
    dim3 g1(DM / 64, NT / 64);
    gemm64<<<g1, 256, 0, stream>>>(x, Wq, q,    nullptr, NT, DM, DM);
    gemm64<<<g1, 256, 0, stream>>>(x, Wk, kbuf, nullptr, NT, DM, DM);

    convertX<<<2048, 256, 0, stream>>>(x, xb, NT * DM);
    transposeW<<<dim3(DM / 32, DM / 32), 256, 0, stream>>>(Wv, WvT, DM);
    transposeW<<<dim3(DM / 32, DM / 32), 256, 0, stream>>>(Wo, WoT, DM);
    gemm_mfma<<<dim3(DM / 64, NT / 64), 256, 0, stream>>>(xb, WvT, nullptr, vb, 1, NT, DM, DM);
    transposeB16<<<dim3(DM / 32, NT / 32), 256, 0, stream>>>(vb, vtb, NT, DM);

    hipMemsetAsync(attn, 0, (size_t)NT * NT * sizeof(float), stream);

    // --- per-head attention ---
    dim3 g2(NT / 64, NT / 64);
    for (int h = 0; h < NH; ++h) {
        qk_head<<<g2, 256, 0, stream>>>(q, kbuf, S, h);
        softmax_acc<<<NT, 256, 0, stream>>>(S, attn);
        pv_mfma<<<dim3(NT / 64, KS), 256, 0, stream>>>(S, vtb, part, h);
        pv_reduce<<<(NT * DH + 255) / 256, 256, 0, stream>>>(part, otmpb, h);
    }

    // --- output projection (bf16 MFMA, bias) ---
    gemm_mfma<<<dim3(DM / 64, NT / 64), 256, 0, stream>>>(otmpb, WoT, bo, out_out, 0, NT, DM, DM);

    // --- pagerank + top-k (fp32, unchanged) ---
    init_dist<<<16, 256, 0, stream>>>(dist0);
    float* da = dist0;
    float* db = dist1;
    for (int it = 0; it < 5; ++it) {
        power_a<<<dim3(16, 32), 256, 0, stream>>>(attn, da, partial);
        power_b<<<16, 256, 0, stream>>>(partial, db);
        float* t = da; da = db; db = t;
    }

    rank_kernel<<<16, 256, 0, stream>>>(da, rank, prank);
    scatter_topk<<<16, 256, 0, stream>>>(rank, prank, out_imps, out_prune,
                                         imp_rows, prune_cols);
    argmax_cols<<<16, 256, 0, stream>>>(attn, imp_rows, maxind);
    finalize<<<16, 256, 0, stream>>>(da, prune_cols, maxind, out_imp, out_simi);
}